// Round 1
// baseline (339.735 us; speedup 1.0000x reference)
//
#include <hip/hip_runtime.h>
#include <hip/hip_bf16.h>
#include <cstdint>
#include <cstddef>

#define NI 8192
#define NC 8192
#define RV 7
#define DD 256

typedef __bf16 bf16x8 __attribute__((ext_vector_type(8)));
typedef float  f32x4  __attribute__((ext_vector_type(4)));

// round-half-up f32->bf16, pack two into one u32 (low = x, high = y)
static __device__ __forceinline__ unsigned pkbf(float x, float y) {
  unsigned a = __float_as_uint(x) + 0x8000u;
  unsigned b = __float_as_uint(y) + 0x8000u;
  return __builtin_amdgcn_perm(b, a, 0x07060302u);
}

// Block tile: 256 imgs x 128 caps, K=256 full. 512 threads = 8 waves (4x2).
// LDS: caps [128][256] bf16 (64KB, staged once, reused over 7 views)
//      imgs chunk [256][64] bf16 double-buffered (2x32KB)
__global__ __launch_bounds__(512, 1)
void mvm_kernel(const float* __restrict__ imgs, const float* __restrict__ caps,
                float* __restrict__ out)
{
  __shared__ __align__(16) char ldsB[128 * 512];        // caps, swizzled rows of 512B
  __shared__ __align__(16) char ldsA[2][256 * 128];     // imgs chunks, swizzled rows of 128B

  const int tid  = threadIdx.x;
  const int lane = tid & 63;
  const int wid  = tid >> 6;
  const int wr   = wid >> 1;   // 0..3: which 64-row imgs strip
  const int wc   = wid & 1;    // 0..1: which 64-col caps strip
  const int i0   = blockIdx.y * 256;
  const int c0   = blockIdx.x * 128;

  // ---- initial stage: caps tile (full K) ----
  #pragma unroll
  for (int it = 0; it < 8; ++it) {
    int c    = tid + it * 512;           // 0..4095
    int row  = c >> 5;                   // 0..127
    int colb = (c & 31) * 16;            // byte col (16B chunks)
    const float* p = caps + (size_t)(c0 + row) * DD + (c & 31) * 8;
    float4 a = *(const float4*)p;
    float4 b = *(const float4*)(p + 4);
    uint4 v;
    v.x = pkbf(a.x, a.y); v.y = pkbf(a.z, a.w);
    v.z = pkbf(b.x, b.y); v.w = pkbf(b.z, b.w);
    *(uint4*)(ldsB + row * 512 + (colb ^ ((row & 7) << 4))) = v;
  }
  // ---- initial stage: imgs chunk (r=0, k0=0) ----
  #pragma unroll
  for (int it = 0; it < 4; ++it) {
    int c    = tid + it * 512;           // 0..2047
    int row  = c >> 3;                   // 0..255
    int colb = (c & 7) * 16;
    const float* p = imgs + ((size_t)(i0 + row) * RV + 0) * DD + (c & 7) * 8;
    float4 a = *(const float4*)p;
    float4 b = *(const float4*)(p + 4);
    uint4 v;
    v.x = pkbf(a.x, a.y); v.y = pkbf(a.z, a.w);
    v.z = pkbf(b.x, b.y); v.w = pkbf(b.z, b.w);
    *(uint4*)(ldsA[0] + row * 128 + (colb ^ ((row & 7) << 4))) = v;
  }
  __syncthreads();

  f32x4 omax[4][4];
  #pragma unroll
  for (int m = 0; m < 4; ++m)
    #pragma unroll
    for (int n = 0; n < 4; ++n)
      #pragma unroll
      for (int j = 0; j < 4; ++j)
        omax[m][n][j] = -3.4e38f;

  f32x4 acc[4][4];
  int cur = 0;
  const int lrow = lane & 15;
  const int lkb  = (lane >> 4) * 16;     // byte offset of this lane's 8-elem k-group

  for (int ch = 0; ch < RV * 4; ++ch) {  // 7 views x 4 k-chunks of 64
    const int kc = ch & 3;
    if (kc == 0) {
      #pragma unroll
      for (int m = 0; m < 4; ++m)
        #pragma unroll
        for (int n = 0; n < 4; ++n)
          acc[m][n] = (f32x4){0.f, 0.f, 0.f, 0.f};
    }

    // -- issue prefetch loads for next chunk (reg-staged, T14 split) --
    const int  chn  = ch + 1;
    const bool hasn = (chn < RV * 4);
    float4 pf[8];
    if (hasn) {
      const int rn = chn >> 2;
      const int kn = (chn & 3) * 64;
      #pragma unroll
      for (int it = 0; it < 4; ++it) {
        int c   = tid + it * 512;
        int row = c >> 3;
        const float* p = imgs + ((size_t)(i0 + row) * RV + rn) * DD + kn + (c & 7) * 8;
        pf[2 * it]     = *(const float4*)p;
        pf[2 * it + 1] = *(const float4*)(p + 4);
      }
    }

    // -- compute current chunk: 2 k-steps x (4x4) MFMA --
    #pragma unroll
    for (int ks = 0; ks < 2; ++ks) {
      bf16x8 af[4], bfr[4];
      #pragma unroll
      for (int m = 0; m < 4; ++m) {
        int row = wr * 64 + m * 16 + lrow;
        af[m] = *(const bf16x8*)(ldsA[cur] + row * 128 + ((ks * 64 + lkb) ^ ((row & 7) << 4)));
      }
      #pragma unroll
      for (int n = 0; n < 4; ++n) {
        int row = wc * 64 + n * 16 + lrow;
        bfr[n] = *(const bf16x8*)(ldsB + row * 512 + ((kc * 128 + ks * 64 + lkb) ^ ((row & 7) << 4)));
      }
      #pragma unroll
      for (int m = 0; m < 4; ++m)
        #pragma unroll
        for (int n = 0; n < 4; ++n)
          acc[m][n] = __builtin_amdgcn_mfma_f32_16x16x32_bf16(af[m], bfr[n], acc[m][n], 0, 0, 0);
    }

    // -- convert + write prefetched chunk into the other buffer --
    if (hasn) {
      #pragma unroll
      for (int it = 0; it < 4; ++it) {
        int c    = tid + it * 512;
        int row  = c >> 3;
        int colb = (c & 7) * 16;
        uint4 v;
        v.x = pkbf(pf[2 * it].x,     pf[2 * it].y);
        v.y = pkbf(pf[2 * it].z,     pf[2 * it].w);
        v.z = pkbf(pf[2 * it + 1].x, pf[2 * it + 1].y);
        v.w = pkbf(pf[2 * it + 1].z, pf[2 * it + 1].w);
        *(uint4*)(ldsA[cur ^ 1] + row * 128 + (colb ^ ((row & 7) << 4))) = v;
      }
    }
    __syncthreads();
    cur ^= 1;

    if (kc == 3) {   // finished one view's full K: fold into running max
      #pragma unroll
      for (int m = 0; m < 4; ++m)
        #pragma unroll
        for (int n = 0; n < 4; ++n)
          #pragma unroll
          for (int j = 0; j < 4; ++j)
            omax[m][n][j] = fmaxf(omax[m][n][j], acc[m][n][j]);
    }
  }

  // ---- epilogue: write out[i][c] ----
  const int rbase = i0 + wr * 64;
  const int cbase = c0 + wc * 64;
  const int lr4   = (lane >> 4) * 4;
  const int lc    = lane & 15;
  #pragma unroll
  for (int m = 0; m < 4; ++m)
    #pragma unroll
    for (int j = 0; j < 4; ++j) {
      size_t ro = (size_t)(rbase + m * 16 + lr4 + j) * NC;
      #pragma unroll
      for (int n = 0; n < 4; ++n)
        out[ro + cbase + n * 16 + lc] = omax[m][n][j];
    }
}

extern "C" void kernel_launch(void* const* d_in, const int* in_sizes, int n_in,
                              void* d_out, int out_size, void* d_ws, size_t ws_size,
                              hipStream_t stream) {
  const float* imgs = (const float*)d_in[0];
  const float* caps = (const float*)d_in[1];
  float* out = (float*)d_out;
  dim3 grid(NC / 128, NI / 256);   // (64, 32)
  mvm_kernel<<<grid, 512, 0, stream>>>(imgs, caps, out);
}

// Round 2
// 289.323 us; speedup vs baseline: 1.1742x; 1.1742x over previous
//
#include <hip/hip_runtime.h>
#include <hip/hip_bf16.h>
#include <cstdint>
#include <cstddef>

#define NI 8192
#define NC 8192
#define RV 7
#define DD 256

typedef __bf16 bf16x8 __attribute__((ext_vector_type(8)));
typedef float  f32x4  __attribute__((ext_vector_type(4)));

// ws layout: imgs images then caps images
//   imgs: per img-block ib (32) x chunk t=r*8+j (56): [4 u][256 row] x 16B = 16KB
//   caps: per cap-block cb (64): [32 u][128 row] x 16B = 64KB
#define IMGS_WS_BYTES (32u * 56u * 16384u)   /* 29,360,128 */
#define CAPS_WS_OFF   IMGS_WS_BYTES
#define CAPS_WS_BYTES (64u * 65536u)         /* 4,194,304 */
#define WS_NEEDED     ((size_t)(IMGS_WS_BYTES + CAPS_WS_BYTES))

static __device__ __forceinline__ unsigned pkbf(float x, float y) {
  unsigned a = __float_as_uint(x) + 0x8000u;
  unsigned b = __float_as_uint(y) + 0x8000u;
  return __builtin_amdgcn_perm(b, a, 0x07060302u);
}

static __device__ __forceinline__ void gload16(const void* g, void* l) {
  __builtin_amdgcn_global_load_lds(
      (const __attribute__((address_space(1))) void*)g,
      (__attribute__((address_space(3))) void*)l, 16, 0, 0);
}

// ---------------- conversion pre-passes (f32 -> bf16, tile-image layout) ---
__global__ __launch_bounds__(256)
void conv_imgs(const float* __restrict__ imgs, uint4* __restrict__ ws) {
  unsigned T = blockIdx.x * 256u + threadIdx.x;   // 0..1,835,007
  unsigned img = T / 224u;                        // 8192 imgs x 224 units
  unsigned rem = T - img * 224u;
  unsigned r  = rem >> 5;                         // view 0..6
  unsigned ju = rem & 31u;                        // k-unit 0..31 (k = ju*8)
  const float* s = imgs + ((size_t)img * RV + r) * DD + ju * 8u;
  float4 a = *(const float4*)s;
  float4 b = *(const float4*)(s + 4);
  uint4 v = { pkbf(a.x, a.y), pkbf(a.z, a.w), pkbf(b.x, b.y), pkbf(b.z, b.w) };
  unsigned ib = img >> 8, lrow = img & 255u;
  unsigned j = ju >> 2, u = ju & 3u;
  unsigned t = r * 8u + j;
  unsigned byteoff = (ib * 56u + t) * 16384u + u * 4096u + lrow * 16u;
  ws[byteoff >> 4] = v;
}

__global__ __launch_bounds__(256)
void conv_caps(const float* __restrict__ caps, uint4* __restrict__ ws) {
  unsigned T = blockIdx.x * 256u + threadIdx.x;   // 0..262,143
  unsigned gr = T >> 5;                           // cap row
  unsigned ju = T & 31u;                          // k-unit
  const float* s = caps + (size_t)gr * DD + ju * 8u;
  float4 a = *(const float4*)s;
  float4 b = *(const float4*)(s + 4);
  uint4 v = { pkbf(a.x, a.y), pkbf(a.z, a.w), pkbf(b.x, b.y), pkbf(b.z, b.w) };
  unsigned cb = gr >> 7, row = gr & 127u;
  unsigned byteoff = cb * 65536u + ju * 2048u + row * 16u;
  ws[byteoff >> 4] = v;
}

// ---------------- main GEMM+max kernel ------------------------------------
// block tile 256 imgs x 128 caps; 8 waves (4m x 2n), wave tile 64x64.
// caps resident 64KB; imgs chunks BK=32, 4 buffers x 16KB; issue t+3 during t,
// counted vmcnt(4), raw barriers, setprio around MFMA clusters.
__global__ __launch_bounds__(512, 2)
void mvm_mfma(const char* __restrict__ wi, const char* __restrict__ wc,
              float* __restrict__ out)
{
  __shared__ __align__(1024) char lds[65536 + 4 * 16384];
  char* const ldsB = lds;
  char* const ldsA = lds + 65536;

  const int tid  = threadIdx.x;
  const int lane = tid & 63;
  const int wid  = tid >> 6;
  const int wr   = wid >> 1;    // 0..3 (img strip)
  const int wq   = wid & 1;     // 0..1 (cap strip)

  const int bid = (int)blockIdx.x;                  // 2048 blocks
  const int swz = (bid & 7) * 256 + (bid >> 3);     // bijective XCD swizzle
  const int ib  = swz >> 6;     // 0..31
  const int cb  = swz & 63;     // 0..63 (consecutive share imgs panel)

  const char* bsrc  = wc + (size_t)cb * 65536u;
  const char* abase = wi + (size_t)ib * (56u * 16384u);

  // prologue: caps (8 loads) + imgs chunks 0..2 (2 loads each)
  #pragma unroll
  for (int l = 0; l < 8; ++l)
    gload16(bsrc + tid * 16 + l * 8192, ldsB + wid * 1024 + l * 8192);
  #pragma unroll
  for (int c = 0; c < 3; ++c) {
    gload16(abase + c * 16384 + tid * 16,        ldsA + c * 16384 + wid * 1024);
    gload16(abase + c * 16384 + tid * 16 + 8192, ldsA + c * 16384 + wid * 1024 + 8192);
  }
  const char* ap = abase + 3 * 16384 + tid * 16;

  asm volatile("s_waitcnt vmcnt(4)" ::: "memory");  // caps + chunk0 landed
  __builtin_amdgcn_s_barrier();
  asm volatile("" ::: "memory");

  const int lrow = lane & 15;
  const int lu   = lane >> 4;   // 8-elem k-group within 32-k chunk
  char* const aB       = ldsA + lu * 4096 + (wr * 64 + lrow) * 16;
  const char* const bB = ldsB + lu * 2048 + (wq * 64 + lrow) * 16;

  f32x4 omax[4][4];
  #pragma unroll
  for (int m = 0; m < 4; ++m)
    #pragma unroll
    for (int n = 0; n < 4; ++n)
      #pragma unroll
      for (int e = 0; e < 4; ++e)
        omax[m][n][e] = -3.4e38f;

  f32x4 acc[4][4];

  for (int i = 0; i < RV; ++i) {
    #pragma unroll
    for (int m = 0; m < 4; ++m)
      #pragma unroll
      for (int n = 0; n < 4; ++n)
        acc[m][n] = (f32x4){0.f, 0.f, 0.f, 0.f};

    #pragma unroll
    for (int j = 0; j < 8; ++j) {
      const int p = j & 3;            // buffer being read (chunk t = i*8+j)
      const int q = (j + 3) & 3;      // buffer being staged (chunk t+3)

      // issue next staging (skip only the very last chunk)
      if (j < 7 || i < 6) {
        gload16(ap,        ldsA + q * 16384 + wid * 1024);
        gload16(ap + 8192, ldsA + q * 16384 + wid * 1024 + 8192);
        ap += 16384;
      }

      // fragment reads (bank-conflict-free unit-major layout, imm offsets)
      bf16x8 a0 = *(const bf16x8*)(aB + p * 16384 + 0 * 256);
      bf16x8 a1 = *(const bf16x8*)(aB + p * 16384 + 1 * 256);
      bf16x8 a2 = *(const bf16x8*)(aB + p * 16384 + 2 * 256);
      bf16x8 a3 = *(const bf16x8*)(aB + p * 16384 + 3 * 256);
      bf16x8 b0 = *(const bf16x8*)(bB + j * 8192 + 0 * 256);
      bf16x8 b1 = *(const bf16x8*)(bB + j * 8192 + 1 * 256);
      bf16x8 b2 = *(const bf16x8*)(bB + j * 8192 + 2 * 256);
      bf16x8 b3 = *(const bf16x8*)(bB + j * 8192 + 3 * 256);

      __builtin_amdgcn_s_barrier();
      asm volatile("" ::: "memory");

      __builtin_amdgcn_s_setprio(1);
      acc[0][0] = __builtin_amdgcn_mfma_f32_16x16x32_bf16(a0, b0, acc[0][0], 0, 0, 0);
      acc[1][0] = __builtin_amdgcn_mfma_f32_16x16x32_bf16(a1, b0, acc[1][0], 0, 0, 0);
      acc[2][0] = __builtin_amdgcn_mfma_f32_16x16x32_bf16(a2, b0, acc[2][0], 0, 0, 0);
      acc[3][0] = __builtin_amdgcn_mfma_f32_16x16x32_bf16(a3, b0, acc[3][0], 0, 0, 0);
      acc[0][1] = __builtin_amdgcn_mfma_f32_16x16x32_bf16(a0, b1, acc[0][1], 0, 0, 0);
      acc[1][1] = __builtin_amdgcn_mfma_f32_16x16x32_bf16(a1, b1, acc[1][1], 0, 0, 0);
      acc[2][1] = __builtin_amdgcn_mfma_f32_16x16x32_bf16(a2, b1, acc[2][1], 0, 0, 0);
      acc[3][1] = __builtin_amdgcn_mfma_f32_16x16x32_bf16(a3, b1, acc[3][1], 0, 0, 0);
      acc[0][2] = __builtin_amdgcn_mfma_f32_16x16x32_bf16(a0, b2, acc[0][2], 0, 0, 0);
      acc[1][2] = __builtin_amdgcn_mfma_f32_16x16x32_bf16(a1, b2, acc[1][2], 0, 0, 0);
      acc[2][2] = __builtin_amdgcn_mfma_f32_16x16x32_bf16(a2, b2, acc[2][2], 0, 0, 0);
      acc[3][2] = __builtin_amdgcn_mfma_f32_16x16x32_bf16(a3, b2, acc[3][2], 0, 0, 0);
      acc[0][3] = __builtin_amdgcn_mfma_f32_16x16x32_bf16(a0, b3, acc[0][3], 0, 0, 0);
      acc[1][3] = __builtin_amdgcn_mfma_f32_16x16x32_bf16(a1, b3, acc[1][3], 0, 0, 0);
      acc[2][3] = __builtin_amdgcn_mfma_f32_16x16x32_bf16(a2, b3, acc[2][3], 0, 0, 0);
      acc[3][3] = __builtin_amdgcn_mfma_f32_16x16x32_bf16(a3, b3, acc[3][3], 0, 0, 0);
      __builtin_amdgcn_s_setprio(0);

      asm volatile("s_waitcnt vmcnt(4)" ::: "memory");  // chunk t+1 landed
      __builtin_amdgcn_s_barrier();
      asm volatile("" ::: "memory");
    }

    #pragma unroll
    for (int m = 0; m < 4; ++m)
      #pragma unroll
      for (int n = 0; n < 4; ++n)
        #pragma unroll
        for (int e = 0; e < 4; ++e)
          omax[m][n][e] = fmaxf(omax[m][n][e], acc[m][n][e]);
  }

  // epilogue
  const int rbase = ib * 256 + wr * 64;
  const int cbase = cb * 128 + wq * 64;
  const int lr4 = (lane >> 4) * 4;
  const int lc  = lane & 15;
  #pragma unroll
  for (int m = 0; m < 4; ++m)
    #pragma unroll
    for (int e = 0; e < 4; ++e) {
      size_t ro = (size_t)(rbase + m * 16 + lr4 + e) * NC;
      #pragma unroll
      for (int n = 0; n < 4; ++n)
        out[ro + cbase + n * 16 + lc] = omax[m][n][e];
    }
}

// ---------------- fallback (round-1 kernel, used if ws too small) ----------
__global__ __launch_bounds__(512, 1)
void mvm_fallback(const float* __restrict__ imgs, const float* __restrict__ caps,
                  float* __restrict__ out)
{
  __shared__ __align__(16) char ldsB[128 * 512];
  __shared__ __align__(16) char ldsA[2][256 * 128];

  const int tid  = threadIdx.x;
  const int lane = tid & 63;
  const int wid  = tid >> 6;
  const int wr   = wid >> 1;
  const int wc   = wid & 1;
  const int i0   = blockIdx.y * 256;
  const int c0   = blockIdx.x * 128;

  #pragma unroll
  for (int it = 0; it < 8; ++it) {
    int c    = tid + it * 512;
    int row  = c >> 5;
    int colb = (c & 31) * 16;
    const float* p = caps + (size_t)(c0 + row) * DD + (c & 31) * 8;
    float4 a = *(const float4*)p;
    float4 b = *(const float4*)(p + 4);
    uint4 v;
    v.x = pkbf(a.x, a.y); v.y = pkbf(a.z, a.w);
    v.z = pkbf(b.x, b.y); v.w = pkbf(b.z, b.w);
    *(uint4*)(ldsB + row * 512 + (colb ^ ((row & 7) << 4))) = v;
  }
  #pragma unroll
  for (int it = 0; it < 4; ++it) {
    int c    = tid + it * 512;
    int row  = c >> 3;
    int colb = (c & 7) * 16;
    const float* p = imgs + ((size_t)(i0 + row) * RV + 0) * DD + (c & 7) * 8;
    float4 a = *(const float4*)p;
    float4 b = *(const float4*)(p + 4);
    uint4 v;
    v.x = pkbf(a.x, a.y); v.y = pkbf(a.z, a.w);
    v.z = pkbf(b.x, b.y); v.w = pkbf(b.z, b.w);
    *(uint4*)(ldsA[0] + row * 128 + (colb ^ ((row & 7) << 4))) = v;
  }
  __syncthreads();

  f32x4 omax[4][4];
  #pragma unroll
  for (int m = 0; m < 4; ++m)
    #pragma unroll
    for (int n = 0; n < 4; ++n)
      #pragma unroll
      for (int j = 0; j < 4; ++j)
        omax[m][n][j] = -3.4e38f;

  f32x4 acc[4][4];
  int cur = 0;
  const int lrow = lane & 15;
  const int lkb  = (lane >> 4) * 16;

  for (int ch = 0; ch < RV * 4; ++ch) {
    const int kc = ch & 3;
    if (kc == 0) {
      #pragma unroll
      for (int m = 0; m < 4; ++m)
        #pragma unroll
        for (int n = 0; n < 4; ++n)
          acc[m][n] = (f32x4){0.f, 0.f, 0.f, 0.f};
    }
    const int  chn  = ch + 1;
    const bool hasn = (chn < RV * 4);
    float4 pf[8];
    if (hasn) {
      const int rn = chn >> 2;
      const int kn = (chn & 3) * 64;
      #pragma unroll
      for (int it = 0; it < 4; ++it) {
        int c   = tid + it * 512;
        int row = c >> 3;
        const float* p = imgs + ((size_t)(i0 + row) * RV + rn) * DD + kn + (c & 7) * 8;
        pf[2 * it]     = *(const float4*)p;
        pf[2 * it + 1] = *(const float4*)(p + 4);
      }
    }
    #pragma unroll
    for (int ks = 0; ks < 2; ++ks) {
      bf16x8 af[4], bfr[4];
      #pragma unroll
      for (int m = 0; m < 4; ++m) {
        int row = wr * 64 + m * 16 + lrow;
        af[m] = *(const bf16x8*)(ldsA[cur] + row * 128 + ((ks * 64 + lkb) ^ ((row & 7) << 4)));
      }
      #pragma unroll
      for (int n = 0; n < 4; ++n) {
        int row = wc * 64 + n * 16 + lrow;
        bfr[n] = *(const bf16x8*)(ldsB + row * 512 + ((kc * 128 + ks * 64 + lkb) ^ ((row & 7) << 4)));
      }
      #pragma unroll
      for (int m = 0; m < 4; ++m)
        #pragma unroll
        for (int n = 0; n < 4; ++n)
          acc[m][n] = __builtin_amdgcn_mfma_f32_16x16x32_bf16(af[m], bfr[n], acc[m][n], 0, 0, 0);
    }
    if (hasn) {
      #pragma unroll
      for (int it = 0; it < 4; ++it) {
        int c    = tid + it * 512;
        int row  = c >> 3;
        int colb = (c & 7) * 16;
        uint4 v;
        v.x = pkbf(pf[2 * it].x,     pf[2 * it].y);
        v.y = pkbf(pf[2 * it].z,     pf[2 * it].w);
        v.z = pkbf(pf[2 * it + 1].x, pf[2 * it + 1].y);
        v.w = pkbf(pf[2 * it + 1].z, pf[2 * it + 1].w);
        *(uint4*)(ldsA[cur ^ 1] + row * 128 + (colb ^ ((row & 7) << 4))) = v;
      }
    }
    __syncthreads();
    cur ^= 1;
    if (kc == 3) {
      #pragma unroll
      for (int m = 0; m < 4; ++m)
        #pragma unroll
        for (int n = 0; n < 4; ++n)
          #pragma unroll
          for (int j = 0; j < 4; ++j)
            omax[m][n][j] = fmaxf(omax[m][n][j], acc[m][n][j]);
    }
  }

  const int rbase = i0 + wr * 64;
  const int cbase = c0 + wc * 64;
  const int lr4   = (lane >> 4) * 4;
  const int lc    = lane & 15;
  #pragma unroll
  for (int m = 0; m < 4; ++m)
    #pragma unroll
    for (int j = 0; j < 4; ++j) {
      size_t ro = (size_t)(rbase + m * 16 + lr4 + j) * NC;
      #pragma unroll
      for (int n = 0; n < 4; ++n)
        out[ro + cbase + n * 16 + lc] = omax[m][n][j];
    }
}

extern "C" void kernel_launch(void* const* d_in, const int* in_sizes, int n_in,
                              void* d_out, int out_size, void* d_ws, size_t ws_size,
                              hipStream_t stream) {
  const float* imgs = (const float*)d_in[0];
  const float* caps = (const float*)d_in[1];
  float* out = (float*)d_out;

  if (ws_size >= WS_NEEDED) {
    char* ws = (char*)d_ws;
    conv_imgs<<<7168, 256, 0, stream>>>(imgs, (uint4*)ws);
    conv_caps<<<1024, 256, 0, stream>>>(caps, (uint4*)(ws + CAPS_WS_OFF));
    mvm_mfma<<<2048, 512, 0, stream>>>((const char*)ws, (const char*)(ws + CAPS_WS_OFF), out);
  } else {
    dim3 grid(NC / 128, NI / 256);
    mvm_fallback<<<grid, 512, 0, stream>>>(imgs, caps, out);
  }
}